// Round 1
// baseline (134.861 us; speedup 1.0000x reference)
//
#include <hip/hip_runtime.h>
#include <cmath>

constexpr int Bn = 4, Cn = 128, Hn = 64, Wn = 64, Kn = 7, NHn = 8, DHn = 16, PADn = 3;
constexpr int HWn = Hn * Wn;              // 4096 pixels per batch
constexpr int TS = 16;                    // pixel tile edge
constexpr int HALO = TS + Kn - 1;         // 22
constexpr int DP = 20;                    // padded depth stride in LDS (16 real + 4 pad)
constexpr int SMEM_ELEMS = HALO * HALO * DP;  // 9680 floats per tensor

// ---------------------------------------------------------------------------
// Kernel 1: fused q/k/v 1x1-conv GEMM.  y[b,o,p] = sum_c W[o,c] x[b,c,p] + bias[o]
// grid: (HW/64, C/64, 3*B); block 256 (16x16 threads, 4x4 microtile)
// ---------------------------------------------------------------------------
__global__ __launch_bounds__(256)
void qkv_gemm(const float* __restrict__ x,
              const float* __restrict__ wq, const float* __restrict__ bq_,
              const float* __restrict__ wk, const float* __restrict__ bk_,
              const float* __restrict__ wv, const float* __restrict__ bv_,
              float* __restrict__ qo, float* __restrict__ ko, float* __restrict__ vo)
{
  constexpr int BM = 64, BN = 64, BK = 16;
  const int z   = blockIdx.z;
  const int mat = z >> 2;      // 0=q, 1=k, 2=v
  const int b   = z & 3;
  const float* Wm   = (mat == 0) ? wq  : (mat == 1) ? wk  : wv;
  const float* bias = (mat == 0) ? bq_ : (mat == 1) ? bk_ : bv_;
  float*       y    = (mat == 0) ? qo  : (mat == 1) ? ko  : vo;

  const float* xb = x + (size_t)b * Cn * HWn;
  float*       yb = y + (size_t)b * Cn * HWn;

  const int m0 = blockIdx.y * BM;
  const int n0 = blockIdx.x * BN;

  __shared__ float As[BK][BM];   // As[k][m]
  __shared__ float Bs[BK][BN];   // Bs[k][n]

  const int tid = threadIdx.x;
  const int tx  = tid & 15;      // n direction
  const int ty  = tid >> 4;      // m direction

  // A-tile load mapping: thread reads a float4 along c (contiguous in W row-major)
  const int a_m = tid >> 2;            // 0..63
  const int a_k = (tid & 3) * 4;       // 0,4,8,12
  // B-tile load mapping: float4 along pixel axis (contiguous in x)
  const int b_k = tid >> 4;            // 0..15
  const int b_n = (tid & 15) * 4;      // 0..60

  float acc[4][4] = {};

  for (int k0 = 0; k0 < Cn; k0 += BK) {
    const float4 av  = *reinterpret_cast<const float4*>(&Wm[(m0 + a_m) * Cn + k0 + a_k]);
    const float4 bv4 = *reinterpret_cast<const float4*>(&xb[(size_t)(k0 + b_k) * HWn + n0 + b_n]);
    __syncthreads();   // previous iteration's reads complete before overwrite
    As[a_k + 0][a_m] = av.x;
    As[a_k + 1][a_m] = av.y;
    As[a_k + 2][a_m] = av.z;
    As[a_k + 3][a_m] = av.w;
    *reinterpret_cast<float4*>(&Bs[b_k][b_n]) = bv4;
    __syncthreads();
#pragma unroll
    for (int kk = 0; kk < BK; ++kk) {
      const float4 a4 = *reinterpret_cast<const float4*>(&As[kk][ty * 4]);
      const float4 b4 = *reinterpret_cast<const float4*>(&Bs[kk][tx * 4]);
      const float aa[4] = {a4.x, a4.y, a4.z, a4.w};
      const float bb[4] = {b4.x, b4.y, b4.z, b4.w};
#pragma unroll
      for (int i = 0; i < 4; ++i)
#pragma unroll
        for (int j = 0; j < 4; ++j)
          acc[i][j] = fmaf(aa[i], bb[j], acc[i][j]);
    }
  }

#pragma unroll
  for (int i = 0; i < 4; ++i) {
    const int m = m0 + ty * 4 + i;
    const float bi = bias[m];
    float4 o;
    o.x = acc[i][0] + bi;
    o.y = acc[i][1] + bi;
    o.z = acc[i][2] + bi;
    o.w = acc[i][3] + bi;
    *reinterpret_cast<float4*>(&yb[(size_t)m * HWn + n0 + tx * 4]) = o;
  }
}

// ---------------------------------------------------------------------------
// Kernel 2: SASA attention.  One block = (batch b, head n, 16x16 pixel tile).
// k/v halo tiles (22x22x16) staged in LDS, depth padded to 20 for alignment +
// bank uniformity.  One thread per pixel: 49 logits -> softmax -> weighted V.
// Out-of-bounds neighbors use k=bk, v=bv (zero-padded input through 1x1 conv).
// ---------------------------------------------------------------------------
__global__ __launch_bounds__(256)
void sasa_attn(const float* __restrict__ q, const float* __restrict__ k,
               const float* __restrict__ v, const float* __restrict__ bk_,
               const float* __restrict__ bv_, const float* __restrict__ pos_h,
               const float* __restrict__ pos_w, float* __restrict__ out)
{
  extern __shared__ float smem[];
  float* ks = smem;               // [hh][ww][d] with depth stride DP
  float* vs = smem + SMEM_ELEMS;

  const int z  = blockIdx.z;
  const int b  = z >> 3;          // NH = 8
  const int n  = z & 7;
  const int h0 = blockIdx.y * TS;
  const int w0 = blockIdx.x * TS;
  const int tid = threadIdx.x;
  const int tx = tid & 15;
  const int ty = tid >> 4;

  const int cbase = n * DHn;
  const size_t plane = (size_t)HWn;
  const float* kb = k + ((size_t)b * Cn + cbase) * plane;
  const float* vb = v + ((size_t)b * Cn + cbase) * plane;

  // ---- stage k/v halo into LDS (consecutive idx -> consecutive w: coalesced)
  for (int idx = tid; idx < HALO * HALO * DHn; idx += 256) {
    const int d   = idx / (HALO * HALO);
    const int rem = idx - d * (HALO * HALO);
    const int hh  = rem / HALO;
    const int ww  = rem - hh * HALO;
    const int gh  = h0 + hh - PADn;
    const int gw  = w0 + ww - PADn;
    const bool inb = (gh >= 0) && (gh < Hn) && (gw >= 0) && (gw < Wn);
    const int lidx = (hh * HALO + ww) * DP + d;
    ks[lidx] = inb ? kb[(size_t)d * plane + gh * Wn + gw] : bk_[cbase + d];
    vs[lidx] = inb ? vb[(size_t)d * plane + gh * Wn + gw] : bv_[cbase + d];
  }

  // ---- q fragment for this thread's pixel (coalesced along w per d)
  const int h = h0 + ty, w = w0 + tx;
  const float* qb = q + ((size_t)b * Cn + cbase) * plane + (size_t)h * Wn + w;
  float qr[DHn];
#pragma unroll
  for (int d = 0; d < DHn; ++d) qr[d] = qb[(size_t)d * plane];

  __syncthreads();

  // ---- logits over 7x7 neighborhood
  float logits[Kn * Kn];
#pragma unroll
  for (int i = 0; i < Kn; ++i) {
    const float ph = pos_h[n * Kn + i];
#pragma unroll
    for (int j = 0; j < Kn; ++j) {
      const float* kp = &ks[((ty + i) * HALO + (tx + j)) * DP];
      const float4 k0 = *reinterpret_cast<const float4*>(kp);
      const float4 k1 = *reinterpret_cast<const float4*>(kp + 4);
      const float4 k2 = *reinterpret_cast<const float4*>(kp + 8);
      const float4 k3 = *reinterpret_cast<const float4*>(kp + 12);
      float acc = qr[0] * k0.x;
      acc = fmaf(qr[1],  k0.y, acc);  acc = fmaf(qr[2],  k0.z, acc);
      acc = fmaf(qr[3],  k0.w, acc);  acc = fmaf(qr[4],  k1.x, acc);
      acc = fmaf(qr[5],  k1.y, acc);  acc = fmaf(qr[6],  k1.z, acc);
      acc = fmaf(qr[7],  k1.w, acc);  acc = fmaf(qr[8],  k2.x, acc);
      acc = fmaf(qr[9],  k2.y, acc);  acc = fmaf(qr[10], k2.z, acc);
      acc = fmaf(qr[11], k2.w, acc);  acc = fmaf(qr[12], k3.x, acc);
      acc = fmaf(qr[13], k3.y, acc);  acc = fmaf(qr[14], k3.z, acc);
      acc = fmaf(qr[15], k3.w, acc);
      logits[i * Kn + j] = acc + ph + pos_w[n * Kn + j];
    }
  }

  // ---- softmax over 49
  float mx = -1e30f;
#pragma unroll
  for (int t = 0; t < Kn * Kn; ++t) mx = fmaxf(mx, logits[t]);
  float sum = 0.0f;
#pragma unroll
  for (int t = 0; t < Kn * Kn; ++t) {
    const float e = __expf(logits[t] - mx);
    logits[t] = e;
    sum += e;
  }
  const float inv = 1.0f / sum;

  // ---- weighted sum of v
  float o[DHn] = {};
#pragma unroll
  for (int i = 0; i < Kn; ++i) {
#pragma unroll
    for (int j = 0; j < Kn; ++j) {
      const float wt = logits[i * Kn + j];
      const float* vp = &vs[((ty + i) * HALO + (tx + j)) * DP];
      const float4 v0 = *reinterpret_cast<const float4*>(vp);
      const float4 v1 = *reinterpret_cast<const float4*>(vp + 4);
      const float4 v2 = *reinterpret_cast<const float4*>(vp + 8);
      const float4 v3 = *reinterpret_cast<const float4*>(vp + 12);
      o[0]  = fmaf(wt, v0.x, o[0]);   o[1]  = fmaf(wt, v0.y, o[1]);
      o[2]  = fmaf(wt, v0.z, o[2]);   o[3]  = fmaf(wt, v0.w, o[3]);
      o[4]  = fmaf(wt, v1.x, o[4]);   o[5]  = fmaf(wt, v1.y, o[5]);
      o[6]  = fmaf(wt, v1.z, o[6]);   o[7]  = fmaf(wt, v1.w, o[7]);
      o[8]  = fmaf(wt, v2.x, o[8]);   o[9]  = fmaf(wt, v2.y, o[9]);
      o[10] = fmaf(wt, v2.z, o[10]);  o[11] = fmaf(wt, v2.w, o[11]);
      o[12] = fmaf(wt, v3.x, o[12]);  o[13] = fmaf(wt, v3.y, o[13]);
      o[14] = fmaf(wt, v3.z, o[14]);  o[15] = fmaf(wt, v3.w, o[15]);
    }
  }

  float* ob = out + ((size_t)b * Cn + cbase) * plane + (size_t)h * Wn + w;
#pragma unroll
  for (int d = 0; d < DHn; ++d) ob[(size_t)d * plane] = o[d] * inv;
}

// ---------------------------------------------------------------------------
extern "C" void kernel_launch(void* const* d_in, const int* in_sizes, int n_in,
                              void* d_out, int out_size, void* d_ws, size_t ws_size,
                              hipStream_t stream) {
  const float* x     = (const float*)d_in[0];
  const float* wq    = (const float*)d_in[1];
  const float* bq    = (const float*)d_in[2];
  const float* wk    = (const float*)d_in[3];
  const float* bk    = (const float*)d_in[4];
  const float* wv    = (const float*)d_in[5];
  const float* bv    = (const float*)d_in[6];
  const float* pos_h = (const float*)d_in[7];
  const float* pos_w = (const float*)d_in[8];
  float* out = (float*)d_out;

  const size_t tensor_elems = (size_t)Bn * Cn * HWn;   // 2,097,152 floats
  float* q = (float*)d_ws;
  float* k = q + tensor_elems;
  float* v = k + tensor_elems;
  // requires ws_size >= 3 * 2097152 * 4 B = 24 MiB

  dim3 g1(HWn / 64, Cn / 64, 3 * Bn);    // (64, 2, 12)
  qkv_gemm<<<g1, 256, 0, stream>>>(x, wq, bq, wk, bk, wv, bv, q, k, v);

  dim3 g2(Wn / TS, Hn / TS, Bn * NHn);   // (4, 4, 32)
  const size_t smem_bytes = 2 * SMEM_ELEMS * sizeof(float);  // 77,440 B
  sasa_attn<<<g2, 256, smem_bytes, stream>>>(q, k, v, bk, bv, pos_h, pos_w, out);
}

// Round 2
// 132.865 us; speedup vs baseline: 1.0150x; 1.0150x over previous
//
#include <hip/hip_runtime.h>
#include <cmath>

constexpr int Bn = 4, Cn = 128, Hn = 64, Wn = 64, Kn = 7, NHn = 8, DHn = 16, PADn = 3;
constexpr int HWn = Hn * Wn;              // 4096 pixels per batch
constexpr int TS = 16;                    // pixel tile edge
constexpr int HALO = TS + Kn - 1;         // 22
constexpr int DP = 20;                    // padded depth stride in LDS (16 real + 4 pad)
constexpr int SMEM_ELEMS = HALO * HALO * DP;  // 9680 floats per tensor

typedef float f32x4 __attribute__((ext_vector_type(4)));
typedef short short8 __attribute__((ext_vector_type(8)));
typedef unsigned int u32x4 __attribute__((ext_vector_type(4)));

__device__ __forceinline__ unsigned short f32_to_bf16_rne(float f) {
  unsigned u = __float_as_uint(f);
  unsigned r = u + 0x7fffu + ((u >> 16) & 1u);
  return (unsigned short)(r >> 16);
}
__device__ __forceinline__ float bf16_to_f32(unsigned short h) {
  return __uint_as_float(((unsigned)h) << 16);
}

// ---------------------------------------------------------------------------
// Prep 1: W matrices -> bf16 hi/lo planes.  Whl[mat][plane][o][c], plane 0=hi 1=lo
// grid (16, 3), block 256
// ---------------------------------------------------------------------------
__global__ __launch_bounds__(256)
void conv_w(const float* __restrict__ wq, const float* __restrict__ wk,
            const float* __restrict__ wv, unsigned short* __restrict__ Whl)
{
  const int mat = blockIdx.y;
  const float* W = (mat == 0) ? wq : (mat == 1) ? wk : wv;
  const int i = (blockIdx.x * 256 + threadIdx.x) * 4;    // 16384 elems per mat
  const f32x4 v = *reinterpret_cast<const f32x4*>(W + i);
  unsigned short h[4], l[4];
#pragma unroll
  for (int j = 0; j < 4; ++j) {
    h[j] = f32_to_bf16_rne(v[j]);
    l[j] = f32_to_bf16_rne(v[j] - bf16_to_f32(h[j]));
  }
  unsigned short* base = Whl + (size_t)mat * 2 * 16384;
  unsigned int hw0 = h[0] | ((unsigned)h[1] << 16), hw1 = h[2] | ((unsigned)h[3] << 16);
  unsigned int lw0 = l[0] | ((unsigned)l[1] << 16), lw1 = l[2] | ((unsigned)l[3] << 16);
  *reinterpret_cast<uint2*>(base + i)          = make_uint2(hw0, hw1);
  *reinterpret_cast<uint2*>(base + 16384 + i)  = make_uint2(lw0, lw1);
}

// ---------------------------------------------------------------------------
// Prep 2: transpose+convert x[b][c][p] -> xThl[b][plane][p][c] bf16 hi/lo.
// Tile 32(c) x 64(p) through LDS.  grid (64, 4, 4), block 256
// ---------------------------------------------------------------------------
__global__ __launch_bounds__(256)
void conv_xT(const float* __restrict__ x, unsigned short* __restrict__ xThl)
{
  __shared__ float sm[32][65];
  const int b   = blockIdx.z;
  const int c0g = blockIdx.y * 32;
  const int p0g = blockIdx.x * 64;
  const int t   = threadIdx.x;
  const float* xb = x + (size_t)b * Cn * HWn;

#pragma unroll
  for (int rep = 0; rep < 2; ++rep) {
    const int cl = rep * 16 + (t >> 4);
    const int pl = (t & 15) * 4;
    const f32x4 v = *reinterpret_cast<const f32x4*>(xb + (size_t)(c0g + cl) * HWn + p0g + pl);
    sm[cl][pl + 0] = v[0]; sm[cl][pl + 1] = v[1];
    sm[cl][pl + 2] = v[2]; sm[cl][pl + 3] = v[3];
  }
  __syncthreads();

  const int pl = t >> 2;           // 0..63
  const int c0 = (t & 3) * 8;      // 0,8,16,24
  u32x4 hw, lw;
#pragma unroll
  for (int j = 0; j < 4; ++j) {
    const float v0 = sm[c0 + 2 * j][pl];
    const float v1 = sm[c0 + 2 * j + 1][pl];
    const unsigned short h0 = f32_to_bf16_rne(v0);
    const unsigned short h1 = f32_to_bf16_rne(v1);
    const unsigned short l0 = f32_to_bf16_rne(v0 - bf16_to_f32(h0));
    const unsigned short l1 = f32_to_bf16_rne(v1 - bf16_to_f32(h1));
    hw[j] = h0 | ((unsigned)h1 << 16);
    lw[j] = l0 | ((unsigned)l1 << 16);
  }
  unsigned short* dst = xThl + (size_t)b * 2 * HWn * Cn + (size_t)(p0g + pl) * Cn + c0g + c0;
  *reinterpret_cast<u32x4*>(dst)             = hw;
  *reinterpret_cast<u32x4*>(dst + HWn * Cn)  = lw;
}

// ---------------------------------------------------------------------------
// Kernel 1: q/k/v projection via split-bf16 MFMA.  One wave = 64x64 output tile.
// C = (Wh+Wl)(Xh+Xl) ~= WhXh + WhXl + WlXh  (lo*lo term ~2^-16, dropped).
// A frag: lane holds A[m=lane&15][k=quad*8+j]; B frag: B[k=quad*8+j][n=lane&15];
// C/D: col=lane&15, row=quad*4+reg (verified layouts).
// grid (64, 2, 12), block 64
// ---------------------------------------------------------------------------
__global__ __launch_bounds__(64)
void qkv_mfma(const unsigned short* __restrict__ Whl,
              const unsigned short* __restrict__ xThl,
              const float* __restrict__ bq_, const float* __restrict__ bk_,
              const float* __restrict__ bv_,
              float* __restrict__ qo, float* __restrict__ ko, float* __restrict__ vo)
{
  const int z   = blockIdx.z;
  const int mat = z >> 2;                  // 0=q,1=k,2=v
  const int b   = z & 3;
  const float* bias = (mat == 0) ? bq_ : (mat == 1) ? bk_ : bv_;
  float* y = ((mat == 0) ? qo : (mat == 1) ? ko : vo) + (size_t)b * Cn * HWn;

  const int lane = threadIdx.x;
  const int r    = lane & 15;
  const int quad = lane >> 4;
  const int mbase = blockIdx.y * 64;
  const int nbase = blockIdx.x * 64;

  const unsigned short* Wm = Whl  + (size_t)mat * 2 * Cn * Cn;
  const unsigned short* Xb = xThl + (size_t)b   * 2 * HWn * Cn;

  f32x4 acc[4][4] = {};

#pragma unroll
  for (int ks = 0; ks < 4; ++ks) {
    const int kk = ks * 32 + quad * 8;
    short8 Ah[4], Al[4], Bh[4], Bl[4];
#pragma unroll
    for (int mt = 0; mt < 4; ++mt) {
      const unsigned short* p = Wm + (size_t)(mbase + mt * 16 + r) * Cn + kk;
      Ah[mt] = *reinterpret_cast<const short8*>(p);
      Al[mt] = *reinterpret_cast<const short8*>(p + Cn * Cn);
    }
#pragma unroll
    for (int nt = 0; nt < 4; ++nt) {
      const unsigned short* p = Xb + (size_t)(nbase + nt * 16 + r) * Cn + kk;
      Bh[nt] = *reinterpret_cast<const short8*>(p);
      Bl[nt] = *reinterpret_cast<const short8*>(p + HWn * Cn);
    }
#pragma unroll
    for (int mt = 0; mt < 4; ++mt)
#pragma unroll
      for (int nt = 0; nt < 4; ++nt) {
        acc[mt][nt] = __builtin_amdgcn_mfma_f32_16x16x32_bf16(Ah[mt], Bh[nt], acc[mt][nt], 0, 0, 0);
        acc[mt][nt] = __builtin_amdgcn_mfma_f32_16x16x32_bf16(Ah[mt], Bl[nt], acc[mt][nt], 0, 0, 0);
        acc[mt][nt] = __builtin_amdgcn_mfma_f32_16x16x32_bf16(Al[mt], Bh[nt], acc[mt][nt], 0, 0, 0);
      }
  }

#pragma unroll
  for (int mt = 0; mt < 4; ++mt) {
#pragma unroll
    for (int reg = 0; reg < 4; ++reg) {
      const int o = mbase + mt * 16 + quad * 4 + reg;
      const float bi = bias[o];
#pragma unroll
      for (int nt = 0; nt < 4; ++nt)
        y[(size_t)o * HWn + nbase + nt * 16 + r] = acc[mt][nt][reg] + bi;
    }
  }
}

// ---------------------------------------------------------------------------
// Kernel 2: SASA attention (unchanged from round 1 — passed, ~10us floor).
// ---------------------------------------------------------------------------
__global__ __launch_bounds__(256)
void sasa_attn(const float* __restrict__ q, const float* __restrict__ k,
               const float* __restrict__ v, const float* __restrict__ bk_,
               const float* __restrict__ bv_, const float* __restrict__ pos_h,
               const float* __restrict__ pos_w, float* __restrict__ out)
{
  extern __shared__ float smem[];
  float* ks = smem;               // [hh][ww][d] with depth stride DP
  float* vs = smem + SMEM_ELEMS;

  const int z  = blockIdx.z;
  const int b  = z >> 3;          // NH = 8
  const int n  = z & 7;
  const int h0 = blockIdx.y * TS;
  const int w0 = blockIdx.x * TS;
  const int tid = threadIdx.x;
  const int tx = tid & 15;
  const int ty = tid >> 4;

  const int cbase = n * DHn;
  const size_t plane = (size_t)HWn;
  const float* kb = k + ((size_t)b * Cn + cbase) * plane;
  const float* vb = v + ((size_t)b * Cn + cbase) * plane;

  for (int idx = tid; idx < HALO * HALO * DHn; idx += 256) {
    const int d   = idx / (HALO * HALO);
    const int rem = idx - d * (HALO * HALO);
    const int hh  = rem / HALO;
    const int ww  = rem - hh * HALO;
    const int gh  = h0 + hh - PADn;
    const int gw  = w0 + ww - PADn;
    const bool inb = (gh >= 0) && (gh < Hn) && (gw >= 0) && (gw < Wn);
    const int lidx = (hh * HALO + ww) * DP + d;
    ks[lidx] = inb ? kb[(size_t)d * plane + gh * Wn + gw] : bk_[cbase + d];
    vs[lidx] = inb ? vb[(size_t)d * plane + gh * Wn + gw] : bv_[cbase + d];
  }

  const int h = h0 + ty, w = w0 + tx;
  const float* qb = q + ((size_t)b * Cn + cbase) * plane + (size_t)h * Wn + w;
  float qr[DHn];
#pragma unroll
  for (int d = 0; d < DHn; ++d) qr[d] = qb[(size_t)d * plane];

  __syncthreads();

  float logits[Kn * Kn];
#pragma unroll
  for (int i = 0; i < Kn; ++i) {
    const float ph = pos_h[n * Kn + i];
#pragma unroll
    for (int j = 0; j < Kn; ++j) {
      const float* kp = &ks[((ty + i) * HALO + (tx + j)) * DP];
      const float4 k0 = *reinterpret_cast<const float4*>(kp);
      const float4 k1 = *reinterpret_cast<const float4*>(kp + 4);
      const float4 k2 = *reinterpret_cast<const float4*>(kp + 8);
      const float4 k3 = *reinterpret_cast<const float4*>(kp + 12);
      float acc = qr[0] * k0.x;
      acc = fmaf(qr[1],  k0.y, acc);  acc = fmaf(qr[2],  k0.z, acc);
      acc = fmaf(qr[3],  k0.w, acc);  acc = fmaf(qr[4],  k1.x, acc);
      acc = fmaf(qr[5],  k1.y, acc);  acc = fmaf(qr[6],  k1.z, acc);
      acc = fmaf(qr[7],  k1.w, acc);  acc = fmaf(qr[8],  k2.x, acc);
      acc = fmaf(qr[9],  k2.y, acc);  acc = fmaf(qr[10], k2.z, acc);
      acc = fmaf(qr[11], k2.w, acc);  acc = fmaf(qr[12], k3.x, acc);
      acc = fmaf(qr[13], k3.y, acc);  acc = fmaf(qr[14], k3.z, acc);
      acc = fmaf(qr[15], k3.w, acc);
      logits[i * Kn + j] = acc + ph + pos_w[n * Kn + j];
    }
  }

  float mx = -1e30f;
#pragma unroll
  for (int t = 0; t < Kn * Kn; ++t) mx = fmaxf(mx, logits[t]);
  float sum = 0.0f;
#pragma unroll
  for (int t = 0; t < Kn * Kn; ++t) {
    const float e = __expf(logits[t] - mx);
    logits[t] = e;
    sum += e;
  }
  const float inv = 1.0f / sum;

  float o[DHn] = {};
#pragma unroll
  for (int i = 0; i < Kn; ++i) {
#pragma unroll
    for (int j = 0; j < Kn; ++j) {
      const float wt = logits[i * Kn + j];
      const float* vp = &vs[((ty + i) * HALO + (tx + j)) * DP];
      const float4 v0 = *reinterpret_cast<const float4*>(vp);
      const float4 v1 = *reinterpret_cast<const float4*>(vp + 4);
      const float4 v2 = *reinterpret_cast<const float4*>(vp + 8);
      const float4 v3 = *reinterpret_cast<const float4*>(vp + 12);
      o[0]  = fmaf(wt, v0.x, o[0]);   o[1]  = fmaf(wt, v0.y, o[1]);
      o[2]  = fmaf(wt, v0.z, o[2]);   o[3]  = fmaf(wt, v0.w, o[3]);
      o[4]  = fmaf(wt, v1.x, o[4]);   o[5]  = fmaf(wt, v1.y, o[5]);
      o[6]  = fmaf(wt, v1.z, o[6]);   o[7]  = fmaf(wt, v1.w, o[7]);
      o[8]  = fmaf(wt, v2.x, o[8]);   o[9]  = fmaf(wt, v2.y, o[9]);
      o[10] = fmaf(wt, v2.z, o[10]);  o[11] = fmaf(wt, v2.w, o[11]);
      o[12] = fmaf(wt, v3.x, o[12]);  o[13] = fmaf(wt, v3.y, o[13]);
      o[14] = fmaf(wt, v3.z, o[14]);  o[15] = fmaf(wt, v3.w, o[15]);
    }
  }

  float* ob = out + ((size_t)b * Cn + cbase) * plane + (size_t)h * Wn + w;
#pragma unroll
  for (int d = 0; d < DHn; ++d) ob[(size_t)d * plane] = o[d] * inv;
}

// ---------------------------------------------------------------------------
extern "C" void kernel_launch(void* const* d_in, const int* in_sizes, int n_in,
                              void* d_out, int out_size, void* d_ws, size_t ws_size,
                              hipStream_t stream) {
  const float* x     = (const float*)d_in[0];
  const float* wq    = (const float*)d_in[1];
  const float* bq    = (const float*)d_in[2];
  const float* wk    = (const float*)d_in[3];
  const float* bk    = (const float*)d_in[4];
  const float* wv    = (const float*)d_in[5];
  const float* bv    = (const float*)d_in[6];
  const float* pos_h = (const float*)d_in[7];
  const float* pos_w = (const float*)d_in[8];
  float* out = (float*)d_out;

  const size_t tensor_elems = (size_t)Bn * Cn * HWn;   // 2,097,152 floats
  float* q = (float*)d_ws;
  float* k = q + tensor_elems;
  float* v = k + tensor_elems;
  unsigned short* Whl  = (unsigned short*)(v + tensor_elems);       // 3*2*128*128
  unsigned short* xThl = Whl + (size_t)3 * 2 * Cn * Cn;             // 4*2*4096*128
  // ws usage: 24 MiB + 192 KiB + 8 MiB ~= 32.2 MiB

  dim3 gw(16, 3, 1);
  conv_w<<<gw, 256, 0, stream>>>(wq, wk, wv, Whl);

  dim3 gx(HWn / 64, Cn / 32, Bn);        // (64, 4, 4)
  conv_xT<<<gx, 256, 0, stream>>>(x, xThl);

  dim3 g1(HWn / 64, Cn / 64, 3 * Bn);    // (64, 2, 12)
  qkv_mfma<<<g1, 64, 0, stream>>>(Whl, xThl, bq, bk, bv, q, k, v);

  dim3 g2(Wn / TS, Hn / TS, Bn * NHn);   // (4, 4, 32)
  const size_t smem_bytes = 2 * SMEM_ELEMS * sizeof(float);  // 77,440 B
  sasa_attn<<<g2, 256, smem_bytes, stream>>>(q, k, v, bk, bv, pos_h, pos_w, out);
}

// Round 3
// 110.832 us; speedup vs baseline: 1.2168x; 1.1988x over previous
//
#include <hip/hip_runtime.h>
#include <cmath>

constexpr int Bn = 4, Cn = 128, Hn = 64, Wn = 64, Kn = 7, NHn = 8, DHn = 16, PADn = 3;
constexpr int HWn = Hn * Wn;              // 4096 pixels per batch
constexpr int TS = 16;                    // pixel tile edge
constexpr int HALO = TS + Kn - 1;         // 22
constexpr int NPIX = HALO * HALO;         // 484 halo pixels
constexpr int PSTRIDE_U16 = 24;           // bf16 LDS pixel stride: 16 data + 8 pad (48 B, 16B-aligned)
constexpr int PSTRIDE_U32 = 12;

typedef float f32x4 __attribute__((ext_vector_type(4)));
typedef short short8 __attribute__((ext_vector_type(8)));
typedef unsigned int u32x4 __attribute__((ext_vector_type(4)));
typedef unsigned short u16x4 __attribute__((ext_vector_type(4)));
typedef unsigned short u16x8 __attribute__((ext_vector_type(8)));

__device__ __forceinline__ unsigned short f32_to_bf16_rne(float f) {
  unsigned u = __float_as_uint(f);
  unsigned r = u + 0x7fffu + ((u >> 16) & 1u);
  return (unsigned short)(r >> 16);
}
__device__ __forceinline__ float bf16_to_f32(unsigned short h) {
  return __uint_as_float(((unsigned)h) << 16);
}
// unpack a uint holding two bf16 (lo = even d, hi = odd d)
__device__ __forceinline__ float bflo(unsigned u) { return __uint_as_float(u << 16); }
__device__ __forceinline__ float bfhi(unsigned u) { return __uint_as_float(u & 0xffff0000u); }

// ---------------------------------------------------------------------------
// Prep (fused): z<4 -> transpose+convert x[b][c][p] to xThl[b][plane][p][c]
// bf16 hi/lo; z==4,y==0,x<48 -> W matrices to bf16 hi/lo planes.
// grid (64, 4, 5), block 256
// ---------------------------------------------------------------------------
__global__ __launch_bounds__(256)
void prep(const float* __restrict__ x,
          const float* __restrict__ wq, const float* __restrict__ wk,
          const float* __restrict__ wv,
          unsigned short* __restrict__ Whl, unsigned short* __restrict__ xThl)
{
  const int t = threadIdx.x;
  if (blockIdx.z == 4) {
    if (blockIdx.y != 0 || blockIdx.x >= 48) return;
    const int mat = blockIdx.x >> 4;
    const int chunk = blockIdx.x & 15;
    const float* W = (mat == 0) ? wq : (mat == 1) ? wk : wv;
    const int i = (chunk * 256 + t) * 4;
    const f32x4 v = *reinterpret_cast<const f32x4*>(W + i);
    unsigned short h[4], l[4];
#pragma unroll
    for (int j = 0; j < 4; ++j) {
      h[j] = f32_to_bf16_rne(v[j]);
      l[j] = f32_to_bf16_rne(v[j] - bf16_to_f32(h[j]));
    }
    unsigned short* base = Whl + (size_t)mat * 2 * 16384;
    *reinterpret_cast<uint2*>(base + i) =
        make_uint2(h[0] | ((unsigned)h[1] << 16), h[2] | ((unsigned)h[3] << 16));
    *reinterpret_cast<uint2*>(base + 16384 + i) =
        make_uint2(l[0] | ((unsigned)l[1] << 16), l[2] | ((unsigned)l[3] << 16));
    return;
  }

  __shared__ float sm[32][65];
  const int b   = blockIdx.z;
  const int c0g = blockIdx.y * 32;
  const int p0g = blockIdx.x * 64;
  const float* xb = x + (size_t)b * Cn * HWn;

#pragma unroll
  for (int rep = 0; rep < 2; ++rep) {
    const int cl = rep * 16 + (t >> 4);
    const int pl = (t & 15) * 4;
    const f32x4 v = *reinterpret_cast<const f32x4*>(xb + (size_t)(c0g + cl) * HWn + p0g + pl);
    sm[cl][pl + 0] = v[0]; sm[cl][pl + 1] = v[1];
    sm[cl][pl + 2] = v[2]; sm[cl][pl + 3] = v[3];
  }
  __syncthreads();

  const int pl = t >> 2;
  const int c0 = (t & 3) * 8;
  u32x4 hw, lw;
#pragma unroll
  for (int j = 0; j < 4; ++j) {
    const float v0 = sm[c0 + 2 * j][pl];
    const float v1 = sm[c0 + 2 * j + 1][pl];
    const unsigned short h0 = f32_to_bf16_rne(v0);
    const unsigned short h1 = f32_to_bf16_rne(v1);
    const unsigned short l0 = f32_to_bf16_rne(v0 - bf16_to_f32(h0));
    const unsigned short l1 = f32_to_bf16_rne(v1 - bf16_to_f32(h1));
    hw[j] = h0 | ((unsigned)h1 << 16);
    lw[j] = l0 | ((unsigned)l1 << 16);
  }
  unsigned short* dst = xThl + (size_t)b * 2 * HWn * Cn + (size_t)(p0g + pl) * Cn + c0g + c0;
  *reinterpret_cast<u32x4*>(dst)            = hw;
  *reinterpret_cast<u32x4*>(dst + HWn * Cn) = lw;
}

// ---------------------------------------------------------------------------
// Kernel 1: q/k/v projection via split-bf16 MFMA (WhXh + WhXl + WlXh).
// One wave = 64x64 output tile.  Outputs:
//   q  -> fp32  [b][n][p][d]  (wave-contiguous 1 KB stores)
//   k,v-> bf16  [b][n][p][d]  (wave-contiguous 512 B stores)
// grid (64, 2, 12), block 64
// ---------------------------------------------------------------------------
__global__ __launch_bounds__(64)
void qkv_mfma(const unsigned short* __restrict__ Whl,
              const unsigned short* __restrict__ xThl,
              const float* __restrict__ bq_, const float* __restrict__ bk_,
              const float* __restrict__ bv_,
              float* __restrict__ qo, unsigned short* __restrict__ kbf,
              unsigned short* __restrict__ vbf)
{
  const int z   = blockIdx.z;
  const int mat = z >> 2;                  // 0=q,1=k,2=v
  const int b   = z & 3;
  const float* bias = (mat == 0) ? bq_ : (mat == 1) ? bk_ : bv_;

  const int lane = threadIdx.x;
  const int r    = lane & 15;
  const int quad = lane >> 4;
  const int mbase = blockIdx.y * 64;
  const int nbase = blockIdx.x * 64;

  const unsigned short* Wm = Whl  + (size_t)mat * 2 * Cn * Cn;
  const unsigned short* Xb = xThl + (size_t)b   * 2 * HWn * Cn;

  f32x4 acc[4][4] = {};

#pragma unroll
  for (int ks = 0; ks < 4; ++ks) {
    const int kk = ks * 32 + quad * 8;
    short8 Ah[4], Al[4], Bh[4], Bl[4];
#pragma unroll
    for (int mt = 0; mt < 4; ++mt) {
      const unsigned short* p = Wm + (size_t)(mbase + mt * 16 + r) * Cn + kk;
      Ah[mt] = *reinterpret_cast<const short8*>(p);
      Al[mt] = *reinterpret_cast<const short8*>(p + Cn * Cn);
    }
#pragma unroll
    for (int nt = 0; nt < 4; ++nt) {
      const unsigned short* p = Xb + (size_t)(nbase + nt * 16 + r) * Cn + kk;
      Bh[nt] = *reinterpret_cast<const short8*>(p);
      Bl[nt] = *reinterpret_cast<const short8*>(p + HWn * Cn);
    }
#pragma unroll
    for (int mt = 0; mt < 4; ++mt)
#pragma unroll
      for (int nt = 0; nt < 4; ++nt) {
        acc[mt][nt] = __builtin_amdgcn_mfma_f32_16x16x32_bf16(Ah[mt], Bh[nt], acc[mt][nt], 0, 0, 0);
        acc[mt][nt] = __builtin_amdgcn_mfma_f32_16x16x32_bf16(Ah[mt], Bl[nt], acc[mt][nt], 0, 0, 0);
        acc[mt][nt] = __builtin_amdgcn_mfma_f32_16x16x32_bf16(Al[mt], Bh[nt], acc[mt][nt], 0, 0, 0);
      }
  }

  // Epilogue: lane holds, for (mt,nt): pixel p = nbase+nt*16+r, head
  // n = blockIdx.y*4+mt, d = quad*4+reg (reg 0..3).  [n][p][d] layout.
#pragma unroll
  for (int mt = 0; mt < 4; ++mt) {
    const int n = blockIdx.y * 4 + mt;
    const f32x4 b4 = *reinterpret_cast<const f32x4*>(bias + mbase + mt * 16 + quad * 4);
#pragma unroll
    for (int nt = 0; nt < 4; ++nt) {
      const int p = nbase + nt * 16 + r;
      const size_t off = ((size_t)((b * NHn + n) * HWn + p)) * DHn + quad * 4;
      f32x4 val = acc[mt][nt] + b4;
      if (mat == 0) {
        *reinterpret_cast<f32x4*>(qo + off) = val;
      } else {
        unsigned short* y = (mat == 1) ? kbf : vbf;
        u16x4 pk;
        pk[0] = f32_to_bf16_rne(val[0]); pk[1] = f32_to_bf16_rne(val[1]);
        pk[2] = f32_to_bf16_rne(val[2]); pk[3] = f32_to_bf16_rne(val[3]);
        *reinterpret_cast<u16x4*>(y + off) = pk;
      }
    }
  }
}

// ---------------------------------------------------------------------------
// Kernel 2: SASA attention.  One block = (batch, head, 16x16 tile).
// k/v halo (22x22 px, 16 bf16 each) staged in LDS at 48 B/pixel stride.
// q read fp32 [n][p][d].  OOB neighbors use k=bk, v=bv.
// grid (4, 4, 32), block 256.  LDS 46.5 KB static.
// ---------------------------------------------------------------------------
__global__ __launch_bounds__(256)
void sasa_attn(const float* __restrict__ q, const unsigned short* __restrict__ kbf,
               const unsigned short* __restrict__ vbf, const float* __restrict__ bk_,
               const float* __restrict__ bv_, const float* __restrict__ pos_h,
               const float* __restrict__ pos_w, float* __restrict__ out)
{
  __shared__ __align__(16) unsigned short ksm[NPIX * PSTRIDE_U16];
  __shared__ __align__(16) unsigned short vsm[NPIX * PSTRIDE_U16];

  const int z  = blockIdx.z;
  const int b  = z >> 3;
  const int n  = z & 7;
  const int h0 = blockIdx.y * TS;
  const int w0 = blockIdx.x * TS;
  const int tid = threadIdx.x;
  const int tx = tid & 15;
  const int ty = tid >> 4;
  const int cbase = n * DHn;

  const unsigned short* kb = kbf + ((size_t)(b * NHn + n) * HWn) * DHn;
  const unsigned short* vb = vbf + ((size_t)(b * NHn + n) * HWn) * DHn;

  // bias halves as packed bf16 (for OOB halo pixels)
  u16x8 kb0, kb1, vb0, vb1;
#pragma unroll
  for (int j = 0; j < 8; ++j) {
    kb0[j] = f32_to_bf16_rne(bk_[cbase + j]);
    kb1[j] = f32_to_bf16_rne(bk_[cbase + 8 + j]);
    vb0[j] = f32_to_bf16_rne(bv_[cbase + j]);
    vb1[j] = f32_to_bf16_rne(bv_[cbase + 8 + j]);
  }

  // ---- stage halo: 484 pixels x 2 halves (16 B each) per tensor
  for (int c = tid; c < NPIX * 2; c += 256) {
    const int pix  = c >> 1;
    const int half = c & 1;
    const int hh = pix / HALO;
    const int ww = pix - hh * HALO;
    const int gh = h0 + hh - PADn;
    const int gw = w0 + ww - PADn;
    const bool inb = (gh >= 0) && (gh < Hn) && (gw >= 0) && (gw < Wn);
    u16x8 kd, vd;
    if (inb) {
      const size_t src = ((size_t)(gh * Wn + gw)) * DHn + half * 8;
      kd = *reinterpret_cast<const u16x8*>(kb + src);
      vd = *reinterpret_cast<const u16x8*>(vb + src);
    } else {
      kd = half ? kb1 : kb0;
      vd = half ? vb1 : vb0;
    }
    const int dst = pix * PSTRIDE_U16 + half * 8;
    *reinterpret_cast<u16x8*>(ksm + dst) = kd;
    *reinterpret_cast<u16x8*>(vsm + dst) = vd;
  }

  // ---- q for this thread's pixel (64 B contiguous)
  const int h = h0 + ty, w = w0 + tx;
  const int p = h * Wn + w;
  const float* qp = q + ((size_t)(b * NHn + n) * HWn + p) * DHn;
  float qr[DHn];
#pragma unroll
  for (int j = 0; j < 4; ++j) {
    const f32x4 t4 = *reinterpret_cast<const f32x4*>(qp + j * 4);
    qr[j * 4 + 0] = t4[0]; qr[j * 4 + 1] = t4[1];
    qr[j * 4 + 2] = t4[2]; qr[j * 4 + 3] = t4[3];
  }

  __syncthreads();

  const unsigned* ksu = reinterpret_cast<const unsigned*>(ksm);
  const unsigned* vsu = reinterpret_cast<const unsigned*>(vsm);

  // ---- logits over 7x7
  float logits[Kn * Kn];
#pragma unroll
  for (int i = 0; i < Kn; ++i) {
    const float ph = pos_h[n * Kn + i];
#pragma unroll
    for (int j = 0; j < Kn; ++j) {
      const int base = ((ty + i) * HALO + (tx + j)) * PSTRIDE_U32;
      const u32x4 a = *reinterpret_cast<const u32x4*>(ksu + base);
      const u32x4 c = *reinterpret_cast<const u32x4*>(ksu + base + 4);
      float acc = qr[0] * bflo(a[0]);
      acc = fmaf(qr[1],  bfhi(a[0]), acc);
      acc = fmaf(qr[2],  bflo(a[1]), acc);  acc = fmaf(qr[3],  bfhi(a[1]), acc);
      acc = fmaf(qr[4],  bflo(a[2]), acc);  acc = fmaf(qr[5],  bfhi(a[2]), acc);
      acc = fmaf(qr[6],  bflo(a[3]), acc);  acc = fmaf(qr[7],  bfhi(a[3]), acc);
      acc = fmaf(qr[8],  bflo(c[0]), acc);  acc = fmaf(qr[9],  bfhi(c[0]), acc);
      acc = fmaf(qr[10], bflo(c[1]), acc);  acc = fmaf(qr[11], bfhi(c[1]), acc);
      acc = fmaf(qr[12], bflo(c[2]), acc);  acc = fmaf(qr[13], bfhi(c[2]), acc);
      acc = fmaf(qr[14], bflo(c[3]), acc);  acc = fmaf(qr[15], bfhi(c[3]), acc);
      logits[i * Kn + j] = acc + ph + pos_w[n * Kn + j];
    }
  }

  // ---- softmax over 49
  float mx = -1e30f;
#pragma unroll
  for (int t = 0; t < Kn * Kn; ++t) mx = fmaxf(mx, logits[t]);
  float sum = 0.0f;
#pragma unroll
  for (int t = 0; t < Kn * Kn; ++t) {
    const float e = __expf(logits[t] - mx);
    logits[t] = e;
    sum += e;
  }
  const float inv = 1.0f / sum;

  // ---- weighted sum of v
  float o[DHn] = {};
#pragma unroll
  for (int i = 0; i < Kn; ++i) {
#pragma unroll
    for (int j = 0; j < Kn; ++j) {
      const float wt = logits[i * Kn + j];
      const int base = ((ty + i) * HALO + (tx + j)) * PSTRIDE_U32;
      const u32x4 a = *reinterpret_cast<const u32x4*>(vsu + base);
      const u32x4 c = *reinterpret_cast<const u32x4*>(vsu + base + 4);
      o[0]  = fmaf(wt, bflo(a[0]), o[0]);   o[1]  = fmaf(wt, bfhi(a[0]), o[1]);
      o[2]  = fmaf(wt, bflo(a[1]), o[2]);   o[3]  = fmaf(wt, bfhi(a[1]), o[3]);
      o[4]  = fmaf(wt, bflo(a[2]), o[4]);   o[5]  = fmaf(wt, bfhi(a[2]), o[5]);
      o[6]  = fmaf(wt, bflo(a[3]), o[6]);   o[7]  = fmaf(wt, bfhi(a[3]), o[7]);
      o[8]  = fmaf(wt, bflo(c[0]), o[8]);   o[9]  = fmaf(wt, bfhi(c[0]), o[9]);
      o[10] = fmaf(wt, bflo(c[1]), o[10]);  o[11] = fmaf(wt, bfhi(c[1]), o[11]);
      o[12] = fmaf(wt, bflo(c[2]), o[12]);  o[13] = fmaf(wt, bfhi(c[2]), o[13]);
      o[14] = fmaf(wt, bflo(c[3]), o[14]);  o[15] = fmaf(wt, bfhi(c[3]), o[15]);
    }
  }

  // ---- out[b][c][h][w], c = n*16+d  (coalesced along w per d)
  float* ob = out + ((size_t)(b * Cn + cbase)) * HWn + p;
#pragma unroll
  for (int d = 0; d < DHn; ++d) ob[(size_t)d * HWn] = o[d] * inv;
}

// ---------------------------------------------------------------------------
extern "C" void kernel_launch(void* const* d_in, const int* in_sizes, int n_in,
                              void* d_out, int out_size, void* d_ws, size_t ws_size,
                              hipStream_t stream) {
  const float* x     = (const float*)d_in[0];
  const float* wq    = (const float*)d_in[1];
  const float* bq    = (const float*)d_in[2];
  const float* wk    = (const float*)d_in[3];
  const float* bk    = (const float*)d_in[4];
  const float* wv    = (const float*)d_in[5];
  const float* bv    = (const float*)d_in[6];
  const float* pos_h = (const float*)d_in[7];
  const float* pos_w = (const float*)d_in[8];
  float* out = (float*)d_out;

  const size_t tensor_elems = (size_t)Bn * Cn * HWn;          // 2,097,152
  float*          q    = (float*)d_ws;                        // 8 MiB
  unsigned short* kbf  = (unsigned short*)(q + tensor_elems); // 4 MiB
  unsigned short* vbf  = kbf + tensor_elems;                  // 4 MiB
  unsigned short* Whl  = vbf + tensor_elems;                  // 192 KiB
  unsigned short* xThl = Whl + (size_t)3 * 2 * Cn * Cn;       // 8 MiB

  dim3 gp(HWn / 64, Cn / 32, Bn + 1);    // (64, 4, 5): z<4 xT, z==4 W
  prep<<<gp, 256, 0, stream>>>(x, wq, wk, wv, Whl, xThl);

  dim3 g1(HWn / 64, Cn / 64, 3 * Bn);    // (64, 2, 12)
  qkv_mfma<<<g1, 64, 0, stream>>>(Whl, xThl, bq, bk, bv, q, kbf, vbf);

  dim3 g2(Wn / TS, Hn / TS, Bn * NHn);   // (4, 4, 32)
  sasa_attn<<<g2, 256, 0, stream>>>(q, kbf, vbf, bk, bv, pos_h, pos_w, out);
}